// Round 21
// baseline (814.139 us; speedup 1.0000x reference)
//
#include <hip/hip_runtime.h>

// B=1024, L=256, F=128, H=256, 3H=768, A=128, CH=256, OUT=512
#define B_ 1024
#define L_ 256
#define F_ 128
#define H_ 256

typedef __bf16 bf16x8 __attribute__((ext_vector_type(8)));
typedef __bf16 bf16x4 __attribute__((ext_vector_type(4)));
typedef float f32x4 __attribute__((ext_vector_type(4)));
typedef int i32x4 __attribute__((ext_vector_type(4)));

#define MFMA16(a, b, c) __builtin_amdgcn_mfma_f32_16x16x32_bf16((a), (b), (c), 0, 0, 0)
#define MFMA_I8(a, b, c) __builtin_amdgcn_mfma_i32_16x16x64_i8((a), (b), (c), 0, 0, 0)
// barrier WITHOUT vmcnt drain: LDS ordering only; VMEM stays in flight
#define BAR_LDS() asm volatile("s_waitcnt lgkmcnt(0)\n\ts_barrier" ::: "memory")

__device__ __forceinline__ float rcp_f(float x) { return __builtin_amdgcn_rcpf(x); }
__device__ __forceinline__ float sigm(float x) { return rcp_f(1.f + __expf(-x)); }
__device__ __forceinline__ float tanh_f(float x) {
  float ax = fabsf(x);
  float e = __expf(-2.f * ax);
  float r = (1.f - e) * rcp_f(1.f + e);
  return copysignf(r, x);
}
__device__ __forceinline__ bf16x8 ld8(const __bf16* p) { return *(const bf16x8*)p; }
__device__ __forceinline__ float wave_max(float v) {
#pragma unroll
  for (int d = 1; d < 64; d <<= 1) v = fmaxf(v, __shfl_xor(v, d));
  return v;
}
__device__ __forceinline__ float wave_sum(float v) {
#pragma unroll
  for (int d = 1; d < 64; d <<= 1) v += __shfl_xor(v, d);
  return v;
}
__device__ __forceinline__ unsigned pack4(float a, float b, float c, float d, float inv) {
  return (unsigned)(unsigned char)(signed char)__float2int_rn(a * inv)
       | ((unsigned)(unsigned char)(signed char)__float2int_rn(b * inv) << 8)
       | ((unsigned)(unsigned char)(signed char)__float2int_rn(c * inv) << 16)
       | ((unsigned)(unsigned char)(signed char)__float2int_rn(d * inv) << 24);
}

// ---- prep: cvt (f32->bf16, transposes) + quant (i8 fragments), one launch ----
__global__ void prep_kernel(const float* __restrict__ wih_f, const float* __restrict__ wa_f,
                            const float* __restrict__ ua_f, const float* __restrict__ w1_f,
                            const float* __restrict__ w2_f, const float* __restrict__ whh_f,
                            const float* __restrict__ wout_f,
                            __bf16* __restrict__ wih, __bf16* __restrict__ wa_t,
                            __bf16* __restrict__ ua_t, __bf16* __restrict__ w1_t,
                            __bf16* __restrict__ w2_t,
                            signed char* __restrict__ wqg_f, signed char* __restrict__ wqo_f,
                            float* __restrict__ dq) {
  if (blockIdx.x < 1472) {
    int i = blockIdx.x * 256 + threadIdx.x;
    if (i < 98304) wih[i] = (__bf16)wih_f[i];                           // [768][128]
    else if (i < 131072) {                                              // Wa[k][a] -> wa_t[a][k]
      int j = i - 98304; int a = j >> 8, k = j & 255;
      wa_t[j] = (__bf16)wa_f[k * 128 + a];
    } else if (i < 147456) {                                            // Ua[f][a] -> ua_t[a][f]
      int j = i - 131072; int a = j >> 7, f = j & 127;
      ua_t[j] = (__bf16)ua_f[f * 128 + a];
    } else if (i < 245760) {                                            // W1[k][c] -> w1_t[c][k]
      int j = i - 147456; int c = j / 384, k = j - c * 384;
      w1_t[j] = (__bf16)w1_f[k * 256 + c];
    } else if (i < 376832) {                                            // W2[k][o] -> w2_t[o][k]
      int j = i - 245760; int o = j >> 8, k = j & 255;
      w2_t[j] = (__bf16)w2_f[k * 512 + o];
    }
    return;
  }
  const int c = (blockIdx.x - 1472) * 256 + threadIdx.x;
  if (c >= 896) return;
  const float* row = (c < 768) ? whh_f + (size_t)c * 256 : wout_f + (size_t)(c - 768) * 256;
  float m = 0.f;
  for (int k4 = 0; k4 < 64; ++k4) {
    float4 v = *(const float4*)(row + k4 * 4);
    m = fmaxf(m, fmaxf(fmaxf(fabsf(v.x), fabsf(v.y)), fmaxf(fabsf(v.z), fabsf(v.w))));
  }
  const float inv = (m > 1e-30f) ? 127.f / m : 0.f;
  dq[c] = m / 16129.f;
  if (c < 768) {
    const int g = c >> 8, cc = c & 255;
    const int t16 = cc >> 4, l15q = cc & 15;
    for (int kt = 0; kt < 4; ++kt)
      for (int lgq = 0; lgq < 4; ++lgq) {
        signed char* dst = wqg_f + (size_t)((((g * 16 + t16) * 4 + kt) * 64) + lgq * 16 + l15q) * 16;
        const float* src = row + kt * 64 + lgq * 16;
        for (int j4 = 0; j4 < 4; ++j4) {
          float4 v = *(const float4*)(src + j4 * 4);
          *(unsigned*)(dst + j4 * 4) = pack4(v.x, v.y, v.z, v.w, inv);
        }
      }
  } else {
    const int oc = c - 768;
    const int t8 = oc >> 4, l15q = oc & 15;
    for (int kt = 0; kt < 4; ++kt)
      for (int lgq = 0; lgq < 4; ++lgq) {
        signed char* dst = wqo_f + (size_t)(((t8 * 4 + kt) * 64) + lgq * 16 + l15q) * 16;
        const float* src = row + kt * 64 + lgq * 16;
        for (int j4 = 0; j4 < 4; ++j4) {
          float4 v = *(const float4*)(src + j4 * 4);
          *(unsigned*)(dst + j4 * 4) = pack4(v.x, v.y, v.z, v.w, inv);
        }
      }
  }
}

// ---- gi precompute (producer layout) + masked zeroing of out ----
__global__ __launch_bounds__(512, 2) void gi_gemm_kernel(
    const float* __restrict__ x, const float* __restrict__ b_ih,
    const float* __restrict__ b_hh, const __bf16* __restrict__ wih,
    const int* __restrict__ tte, __bf16* __restrict__ gi,
    float* __restrict__ out) {
  const int tid = threadIdx.x;
  const int lane = tid & 63, w = tid >> 6;
  const int l15 = lane & 15, lg = lane >> 4, kofs = lg * 8;
  const int bblk = blockIdx.x & 63, tgrp = blockIdx.x >> 6;
  const int b0 = bblk * 16;

  // zero out[b][t][:] for this stripe's (b,t) with t >= tte[b]
  {
    const int pr = tid >> 1, ph = tid & 1;
    const int bl = pr >> 4, tl = pr & 15;
    const int bb = b0 + bl, tt = tgrp * 16 + tl;
    if (tt >= tte[bb]) {
      float4* dst = (float4*)(out + ((size_t)bb * L_ + tt) * F_) + ph * 16;
#pragma unroll
      for (int i = 0; i < 16; ++i) dst[i] = float4{0.f, 0.f, 0.f, 0.f};
    }
  }

  int tmaxB = 0;
  for (int i = 0; i < 16; ++i) tmaxB = max(tmaxB, tte[b0 + i]);
  if (tgrp * 16 > tmaxB) return;

  bf16x8 wf[6][4];
  float bias[6];
#pragma unroll
  for (int tile = 0; tile < 6; ++tile) {
    const int gate = tile >> 1;
    const int c = w * 32 + (tile & 1) * 16 + l15;
    const int col = gate * 256 + c;
#pragma unroll
    for (int kt = 0; kt < 4; ++kt) wf[tile][kt] = ld8(wih + (size_t)col * 128 + kt * 32 + kofs);
    bias[tile] = (gate == 0) ? b_ih[c] + b_hh[c]
               : (gate == 1) ? b_ih[256 + c] + b_hh[256 + c]
                             : b_ih[512 + c];
  }

#pragma unroll 1
  for (int ti = 0; ti < 16; ++ti) {
    const int t = tgrp * 16 + ti;
    if (t > tmaxB) break;
    const float* xb = x + ((size_t)(b0 + l15) * L_ + t) * F_ + kofs;
    bf16x8 xfr[4];
#pragma unroll
    for (int kt = 0; kt < 4; ++kt) {
      float4 a = *(const float4*)(xb + kt * 32);
      float4 b = *(const float4*)(xb + kt * 32 + 4);
      xfr[kt][0] = (__bf16)a.x; xfr[kt][1] = (__bf16)a.y;
      xfr[kt][2] = (__bf16)a.z; xfr[kt][3] = (__bf16)a.w;
      xfr[kt][4] = (__bf16)b.x; xfr[kt][5] = (__bf16)b.y;
      xfr[kt][6] = (__bf16)b.z; xfr[kt][7] = (__bf16)b.w;
    }
    f32x4 acc[6];
#pragma unroll
    for (int tile = 0; tile < 6; ++tile) {
      acc[tile][0] = bias[tile]; acc[tile][1] = bias[tile];
      acc[tile][2] = bias[tile]; acc[tile][3] = bias[tile];
    }
#pragma unroll
    for (int kt = 0; kt < 4; ++kt)
#pragma unroll
      for (int tile = 0; tile < 6; ++tile)
        acc[tile] = MFMA16(xfr[kt], wf[tile][kt], acc[tile]);

    const size_t chunk = (((size_t)t * 64 + bblk) * 8 + w) * 6;
#pragma unroll
    for (int tile = 0; tile < 6; ++tile) {
      bf16x4 pk;
      pk[0] = (__bf16)acc[tile][0]; pk[1] = (__bf16)acc[tile][1];
      pk[2] = (__bf16)acc[tile][2]; pk[3] = (__bf16)acc[tile][3];
      *(bf16x4*)(gi + (chunk + tile) * 256 + (lg * 16 + l15) * 4) = pk;
    }
  }
}

// ---- mega: blocks 0..255 = gru256v4 (+release flag); blocks 256..511 =
// decoder3 (spin-acquire flag for its batch group, then unchanged phases;
// all barriers unconditional for the 1024-thread shape). Deadlock-free:
// gru blocks all resident at dispatch, never wait; decoder waits only on
// running gru blocks; spin has a bail guard. ----
__global__ __launch_bounds__(1024) void mega_kernel(
    const float* __restrict__ x, const int* __restrict__ tte,
    const float* __restrict__ b_hh,
    const signed char* __restrict__ wqg_f, const signed char* __restrict__ wqo_f,
    const float* __restrict__ dq, const __bf16* __restrict__ gi,
    const float* __restrict__ b_out,
    const __bf16* __restrict__ wa_t, const __bf16* __restrict__ ua_t,
    const __bf16* __restrict__ w1_t, const __bf16* __restrict__ w2_t,
    const float* __restrict__ va, const float* __restrict__ b1,
    const float* __restrict__ b2,
    __bf16* __restrict__ hid, float* __restrict__ out, float* __restrict__ fht,
    int* __restrict__ flags) {
  // gru LDS
  __shared__ signed char hb[2][4][288];
  // decoder LDS
  __shared__ __bf16 catb[16][392];
  __shared__ float u_s[4][128];
  __shared__ float sa[4][256];
  __shared__ __bf16 z1b[16][264];
  __shared__ float lg2[4][516];
  __shared__ float ctxp[2][4][256];
  __shared__ float va_s[128];
  __shared__ int tte_s[4];

  const int tid = threadIdx.x;
  const int lane = tid & 63, w = tid >> 6;
  const int l15 = lane & 15, lg = lane >> 4, kofs = lg * 8;

  if (blockIdx.x < 256) {
    // ================= gru256v4 =================
    const int blk = blockIdx.x;
    const int b0 = blk * 4;

    for (int i = tid; i < 2 * 4 * 288; i += 1024) ((signed char*)hb)[i] = 0;

    i32x4 wR[4], wZ[4], wN[4];
#pragma unroll
    for (int kt = 0; kt < 4; ++kt) {
      wR[kt] = *(const i32x4*)(wqg_f + (size_t)((((0 * 16 + w) * 4 + kt) * 64) + lane) * 16);
      wZ[kt] = *(const i32x4*)(wqg_f + (size_t)((((1 * 16 + w) * 4 + kt) * 64) + lane) * 16);
      wN[kt] = *(const i32x4*)(wqg_f + (size_t)((((2 * 16 + w) * 4 + kt) * 64) + lane) * 16);
    }
    const int ocol = (w & 7) * 16 + l15;
    i32x4 ow[4];
#pragma unroll
    for (int kt = 0; kt < 4; ++kt)
      ow[kt] = *(const i32x4*)(wqo_f + (size_t)(((w & 7) * 4 + kt) * 64 + lane) * 16);
    const float dqo = dq[768 + ocol];
    const float bo = b_out[ocol];
    int tteO[4];
#pragma unroll
    for (int r = 0; r < 4; ++r) tteO[r] = tte[b0 + r];
    float* outp = out + ((size_t)b0 * L_) * F_ + ocol;

    const int groww = lane >> 4, gcolw = w * 16 + (lane & 15);
    const float dqR = dq[gcolw], dqZ = dq[256 + gcolw], dqN = dq[512 + gcolw];
    const float bhn = b_hh[512 + gcolw];
    const int tteL = tte[b0 + groww];
    int tmax = 0;
#pragma unroll
    for (int i = 0; i < 4; ++i) tmax = max(tmax, tte[b0 + i]);

    const size_t gb0 = (((size_t)(blk >> 2) * 8 + (gcolw >> 5)) * 6 + ((gcolw >> 4) & 1)) * 256
                     + (size_t)((blk & 3) * 16 + (gcolw & 15)) * 4 + groww;
    const __bf16* gp = gi + gb0;
    __bf16 gRn = gp[0], gZn = gp[512], gNn = gp[1024];
    const __bf16* gpp = gp + 786432;

    __bf16* hidp = hid + ((size_t)(b0 + groww) * L_) * H_ + gcolw;
    float hprev = 0.f;

    __syncthreads();

#pragma unroll 1
    for (int t = 0; t < tmax; ++t) {
      const int c = t & 1, nc = c ^ 1;

      const float grf = (float)gRn, gzf = (float)gZn, gnf = (float)gNn;
      gRn = gpp[0]; gZn = gpp[512]; gNn = gpp[1024];
      if (t < 254) gpp += 786432;

      i32x4 aR = {0, 0, 0, 0}, aZ = {0, 0, 0, 0}, aN = {0, 0, 0, 0}, ac = {0, 0, 0, 0};
#pragma unroll
      for (int kt = 0; kt < 4; ++kt) {
        const i32x4 hA = *(const i32x4*)&hb[c][l15 & 3][kt * 64 + lg * 16];
        aR = MFMA_I8(hA, wR[kt], aR);
        aZ = MFMA_I8(hA, wZ[kt], aZ);
        aN = MFMA_I8(hA, wN[kt], aN);
        if (w < 8) ac = MFMA_I8(hA, ow[kt], ac);
      }
      if (w < 8 && t > 0) {
        if (lg == 0) {
#pragma unroll
          for (int r = 0; r < 4; ++r)
            if (t - 1 < tteO[r]) outp[(size_t)r * (L_ * F_)] = (float)ac[r] * dqo + bo;
        }
        outp += F_;
      }

      {
        const int srcl = lane & 15;
        int tR0 = __shfl(aR[0], srcl), tR1 = __shfl(aR[1], srcl);
        int tR2 = __shfl(aR[2], srcl), tR3 = __shfl(aR[3], srcl);
        int tZ0 = __shfl(aZ[0], srcl), tZ1 = __shfl(aZ[1], srcl);
        int tZ2 = __shfl(aZ[2], srcl), tZ3 = __shfl(aZ[3], srcl);
        int tN0 = __shfl(aN[0], srcl), tN1 = __shfl(aN[1], srcl);
        int tN2 = __shfl(aN[2], srcl), tN3 = __shfl(aN[3], srcl);
        const int vR = groww == 0 ? tR0 : groww == 1 ? tR1 : groww == 2 ? tR2 : tR3;
        const int vZ = groww == 0 ? tZ0 : groww == 1 ? tZ1 : groww == 2 ? tZ2 : tZ3;
        const int vN = groww == 0 ? tN0 : groww == 1 ? tN1 : groww == 2 ? tN2 : tN3;

        const float rg = sigm(grf + (float)vR * dqR);
        const float zg = sigm(gzf + (float)vZ * dqZ);
        const float ng = tanh_f(gnf + rg * ((float)vN * dqN + bhn));
        const float hnew = zg * (hprev - ng) + ng;
        const float hw = (t < tteL) ? hnew : hprev;
        hprev = hw;
        hb[nc][groww][gcolw] = (signed char)__float2int_rn(hw * 127.f);
        if (t < tteL) *hidp = (__bf16)hw;
        hidp += H_;
      }
      BAR_LDS();
    }

    // epilogue out-proj for final step
    if (w < 8 && tmax > 0) {
      const int cf = tmax & 1;
      i32x4 ac = {0, 0, 0, 0};
#pragma unroll
      for (int kt = 0; kt < 4; ++kt) {
        const i32x4 hA = *(const i32x4*)&hb[cf][l15 & 3][kt * 64 + lg * 16];
        ac = MFMA_I8(hA, ow[kt], ac);
      }
      if (lg == 0) {
#pragma unroll
        for (int r = 0; r < 4; ++r)
          if (tmax - 1 < tteO[r]) outp[(size_t)r * (L_ * F_)] = (float)ac[r] * dqo + bo;
      }
    }

    __syncthreads();   // full drain (vmcnt) of hid/out stores
    if (tid == 0)
      __hip_atomic_store(&flags[blk], 1, __ATOMIC_RELEASE, __HIP_MEMORY_SCOPE_AGENT);
    return;
  }

  // ================= decoder3 (batch group = blockIdx.x - 256) =================
  const int grp = blockIdx.x - 256;
  const int b0 = grp * 4;

  if (tid == 0) {
    long guard = 0;
    while (__hip_atomic_load(&flags[grp], __ATOMIC_ACQUIRE, __HIP_MEMORY_SCOPE_AGENT) == 0)
      if (++guard > 300000000L) break;   // bail -> wrong result, never a hang
  }
  __syncthreads();

  if (tid < 4) tte_s[tid] = tte[b0 + tid];
  if (tid < 128) va_s[tid] = va[tid];
  if (tid < 392)
    for (int r = 4; r < 16; ++r) catb[r][tid] = (__bf16)0.f;
  if (tid < 264)
    for (int r = 4; r < 16; ++r) z1b[r][tid] = (__bf16)0.f;
  __syncthreads();

  // Phase A: gather last -> catb[b][256+f]
  if (tid < 512) {
    const int row = tid >> 7, c = tid & 127;
    catb[row][256 + c] = (__bf16)x[((size_t)(b0 + row) * L_ + tte_s[row]) * F_ + c];
  }
  __syncthreads();

  // Phase B: u[4][128] = last @ Ua
  if (w < 8) {
    f32x4 uacc = {0, 0, 0, 0};
#pragma unroll
    for (int kt = 0; kt < 4; ++kt) {
      const bf16x8 af = *(const bf16x8*)&catb[l15][256 + kt * 32 + kofs];
      const bf16x8 bf = ld8(ua_t + (size_t)(w * 16 + l15) * 128 + kt * 32 + kofs);
      uacc = MFMA16(af, bf, uacc);
    }
#pragma unroll
    for (int r = 0; r < 4; ++r) {
      const int row = 4 * lg + r;
      if (row < 4) u_s[row][w * 16 + l15] = uacc[r];
    }
  }
  __syncthreads();

  // Phase C: attention scores (4 b x 16 mtiles = 64 pairs / 8 waves)
  if (w < 8) {
    bf16x8 zero8;
#pragma unroll
    for (int j = 0; j < 8; ++j) zero8[j] = (__bf16)0.f;
#pragma unroll 1
    for (int it = 0; it < 8; ++it) {
      const int pair = it * 8 + w;
      const int b = pair >> 4, mtile = pair & 15;
      const int tteB = tte_s[b];
      const int trow = mtile * 16 + l15;
      const __bf16* hrow = hid + ((size_t)(b0 + b) * L_ + trow) * H_ + kofs;
      bf16x8 af[8];
#pragma unroll
      for (int kt = 0; kt < 8; ++kt) af[kt] = (trow < tteB) ? ld8(hrow + kt * 32) : zero8;
      f32x4 sacc[8];
#pragma unroll
      for (int ct = 0; ct < 8; ++ct) { sacc[ct][0] = 0; sacc[ct][1] = 0; sacc[ct][2] = 0; sacc[ct][3] = 0; }
#pragma unroll
      for (int kt = 0; kt < 8; ++kt)
#pragma unroll
        for (int ct = 0; ct < 8; ++ct)
          sacc[ct] = MFMA16(af[kt], ld8(wa_t + (size_t)(ct * 16 + l15) * 256 + kt * 32 + kofs), sacc[ct]);
      float sp[4] = {0, 0, 0, 0};
#pragma unroll
      for (int ct = 0; ct < 8; ++ct) {
        const int a = ct * 16 + l15;
        const float ua = u_s[b][a], vv = va_s[a];
#pragma unroll
        for (int r = 0; r < 4; ++r) sp[r] += tanh_f(sacc[ct][r] + ua) * vv;
      }
#pragma unroll
      for (int r = 0; r < 4; ++r) {
        sp[r] += __shfl_xor(sp[r], 1);
        sp[r] += __shfl_xor(sp[r], 2);
        sp[r] += __shfl_xor(sp[r], 4);
        sp[r] += __shfl_xor(sp[r], 8);
      }
      if (l15 == 0) {
#pragma unroll
        for (int r = 0; r < 4; ++r) sa[b][mtile * 16 + 4 * lg + r] = sp[r];
      }
    }
  }
  __syncthreads();

  // Phase D: softmax per b (waves 0-3)
  if (w < 4) {
    float sv[4];
#pragma unroll
    for (int j = 0; j < 4; ++j) sv[j] = sa[w][lane + 64 * j];
    float mx = fmaxf(fmaxf(sv[0], sv[1]), fmaxf(sv[2], sv[3]));
    mx = wave_max(mx);
    float es[4], ss = 0.f;
#pragma unroll
    for (int j = 0; j < 4; ++j) { es[j] = __expf(sv[j] - mx); ss += es[j]; }
    ss = wave_sum(ss);
    const float inv = rcp_f(ss);
#pragma unroll
    for (int j = 0; j < 4; ++j) sa[w][lane + 64 * j] = es[j] * inv;
  }
  __syncthreads();

  // Phase E: ctx partials — wave w (<8): b = w&3, half = w>>2
  if (w < 8) {
    const int be = w & 3, half = w >> 2;
    const int tteE = tte_s[be];
    float c4[4] = {0.f, 0.f, 0.f, 0.f};
    const __bf16* hp = hid + ((size_t)(b0 + be) * L_ + half) * H_ + lane * 4;
#pragma unroll 2
    for (int t = half; t < tteE; t += 2) {
      const float al = sa[be][t];
      const bf16x4 hv = *(const bf16x4*)hp;
      hp += 2 * H_;
#pragma unroll
      for (int j = 0; j < 4; ++j) c4[j] += al * (float)hv[j];
    }
#pragma unroll
    for (int j = 0; j < 4; ++j) ctxp[half][be][lane * 4 + j] = c4[j];
  }
  __syncthreads();
  if (w < 4) {
#pragma unroll
    for (int j = 0; j < 4; ++j)
      catb[w][lane * 4 + j] = (__bf16)(ctxp[0][w][lane * 4 + j] + ctxp[1][w][lane * 4 + j]);
  }
  __syncthreads();

  // Phase F: z1 = relu([ctx|last] @ W1 + b1)
  if (w < 8) {
#pragma unroll 1
    for (int half = 0; half < 2; ++half) {
      const int nt = w * 2 + half;
      f32x4 zacc = {0, 0, 0, 0};
#pragma unroll
      for (int kt = 0; kt < 12; ++kt) {
        const bf16x8 af = *(const bf16x8*)&catb[l15][kt * 32 + kofs];
        const bf16x8 bf = ld8(w1_t + (size_t)(nt * 16 + l15) * 384 + kt * 32 + kofs);
        zacc = MFMA16(af, bf, zacc);
      }
      const float bb = b1[nt * 16 + l15];
#pragma unroll
      for (int r = 0; r < 4; ++r) {
        const int row = 4 * lg + r;
        if (row < 4) z1b[row][nt * 16 + l15] = (__bf16)fmaxf(zacc[r] + bb, 0.f);
      }
    }
  }
  __syncthreads();

  // Phase G: logits + final softmax
  if (w < 8) {
#pragma unroll 1
    for (int q = 0; q < 4; ++q) {
      const int nt = w * 4 + q;
      f32x4 oacc = {0, 0, 0, 0};
#pragma unroll
      for (int kt = 0; kt < 8; ++kt) {
        const bf16x8 af = *(const bf16x8*)&z1b[l15][kt * 32 + kofs];
        const bf16x8 bf = ld8(w2_t + (size_t)(nt * 16 + l15) * 256 + kt * 32 + kofs);
        oacc = MFMA16(af, bf, oacc);
      }
      const float bb = b2[nt * 16 + l15];
#pragma unroll
      for (int r = 0; r < 4; ++r) {
        const int row = 4 * lg + r;
        if (row < 4) lg2[row][nt * 16 + l15] = oacc[r] + bb;
      }
    }
  }
  __syncthreads();
  if (w < 4) {
    float lv[8];
    float mx = -1e30f;
#pragma unroll
    for (int j = 0; j < 8; ++j) { lv[j] = lg2[w][lane + 64 * j]; mx = fmaxf(mx, lv[j]); }
    mx = wave_max(mx);
    float s2 = 0.f;
#pragma unroll
    for (int j = 0; j < 8; ++j) { lv[j] = __expf(lv[j] - mx); s2 += lv[j]; }
    s2 = wave_sum(s2);
    const float inv2 = rcp_f(s2);
#pragma unroll
    for (int j = 0; j < 8; ++j)
      fht[(size_t)(b0 + w) * 512 + lane + 64 * j] = lv[j] * inv2;
  }
}

extern "C" void kernel_launch(void* const* d_in, const int* in_sizes, int n_in,
                              void* d_out, int out_size, void* d_ws, size_t ws_size,
                              hipStream_t stream) {
  const float* x = (const float*)d_in[0];
  const int* tte = (const int*)d_in[1];
  const float* W_ih = (const float*)d_in[2];
  const float* W_hh = (const float*)d_in[3];
  const float* b_ih = (const float*)d_in[4];
  const float* b_hh = (const float*)d_in[5];
  const float* W_out = (const float*)d_in[6];
  const float* b_out = (const float*)d_in[7];
  const float* Wa = (const float*)d_in[8];
  const float* Ua = (const float*)d_in[9];
  const float* va = (const float*)d_in[10];
  const float* W1 = (const float*)d_in[11];
  const float* b1 = (const float*)d_in[12];
  const float* W2 = (const float*)d_in[13];
  const float* b2 = (const float*)d_in[14];

  char* ws = (char*)d_ws;
  __bf16* wih = (__bf16*)(ws + 0);                  // 196608
  __bf16* wa_t = (__bf16*)(ws + 196608);            // 65536
  __bf16* ua_t = (__bf16*)(ws + 262144);            // 32768
  __bf16* w1_t = (__bf16*)(ws + 294912);            // 196608
  __bf16* w2_t = (__bf16*)(ws + 491520);            // 262144
  signed char* wqg_f = (signed char*)(ws + 753664); // 196608
  signed char* wqo_f = (signed char*)(ws + 950272); // 32768
  float* dq = (float*)(ws + 983040);                // 3584 used
  int* flags = (int*)(ws + 987136);                 // 1024 B (256 flags)
  __bf16* hid = (__bf16*)(ws + 1048576);            // 134217728
  __bf16* gi = (__bf16*)(ws + 135266304);           // 402653184

  float* out = (float*)d_out;
  float* fht = out + (size_t)33554432;

  hipMemsetAsync(flags, 0, 1024, stream);           // gru-done flags (per launch)
  prep_kernel<<<1476, 256, 0, stream>>>(W_ih, Wa, Ua, W1, W2, W_hh, W_out,
                                        wih, wa_t, ua_t, w1_t, w2_t,
                                        wqg_f, wqo_f, dq);
  gi_gemm_kernel<<<1024, 512, 0, stream>>>(x, b_ih, b_hh, wih, tte, gi, out);
  mega_kernel<<<512, 1024, 0, stream>>>(x, tte, b_hh, wqg_f, wqo_f, dq, gi,
                                        b_out, wa_t, ua_t, w1_t, w2_t, va, b1, b2,
                                        hid, out, fht, flags);
}

// Round 22
// 710.042 us; speedup vs baseline: 1.1466x; 1.1466x over previous
//
#include <hip/hip_runtime.h>

// B=1024, L=256, F=128, H=256, 3H=768, A=128, CH=256, OUT=512
#define B_ 1024
#define L_ 256
#define F_ 128
#define H_ 256

typedef __bf16 bf16x8 __attribute__((ext_vector_type(8)));
typedef __bf16 bf16x4 __attribute__((ext_vector_type(4)));
typedef float f32x4 __attribute__((ext_vector_type(4)));
typedef int i32x4 __attribute__((ext_vector_type(4)));

#define MFMA16(a, b, c) __builtin_amdgcn_mfma_f32_16x16x32_bf16((a), (b), (c), 0, 0, 0)
#define MFMA_I8(a, b, c) __builtin_amdgcn_mfma_i32_16x16x64_i8((a), (b), (c), 0, 0, 0)
// barrier WITHOUT vmcnt drain: LDS ordering only; VMEM stays in flight
#define BAR_LDS() asm volatile("s_waitcnt lgkmcnt(0)\n\ts_barrier" ::: "memory")

__device__ __forceinline__ float rcp_f(float x) { return __builtin_amdgcn_rcpf(x); }
__device__ __forceinline__ float sigm(float x) { return rcp_f(1.f + __expf(-x)); }
__device__ __forceinline__ float tanh_f(float x) {
  float ax = fabsf(x);
  float e = __expf(-2.f * ax);
  float r = (1.f - e) * rcp_f(1.f + e);
  return copysignf(r, x);
}
__device__ __forceinline__ bf16x8 ld8(const __bf16* p) { return *(const bf16x8*)p; }
__device__ __forceinline__ float wave_max(float v) {
#pragma unroll
  for (int d = 1; d < 64; d <<= 1) v = fmaxf(v, __shfl_xor(v, d));
  return v;
}
__device__ __forceinline__ float wave_sum(float v) {
#pragma unroll
  for (int d = 1; d < 64; d <<= 1) v += __shfl_xor(v, d);
  return v;
}
__device__ __forceinline__ unsigned pack4(float a, float b, float c, float d, float inv) {
  return (unsigned)(unsigned char)(signed char)__float2int_rn(a * inv)
       | ((unsigned)(unsigned char)(signed char)__float2int_rn(b * inv) << 8)
       | ((unsigned)(unsigned char)(signed char)__float2int_rn(c * inv) << 16)
       | ((unsigned)(unsigned char)(signed char)__float2int_rn(d * inv) << 24);
}

// ---- prep: cvt (f32->bf16, transposes) + quant (i8 fragments), one launch ----
__global__ void prep_kernel(const float* __restrict__ wih_f, const float* __restrict__ wa_f,
                            const float* __restrict__ ua_f, const float* __restrict__ w1_f,
                            const float* __restrict__ w2_f, const float* __restrict__ whh_f,
                            const float* __restrict__ wout_f,
                            __bf16* __restrict__ wih, __bf16* __restrict__ wa_t,
                            __bf16* __restrict__ ua_t, __bf16* __restrict__ w1_t,
                            __bf16* __restrict__ w2_t,
                            signed char* __restrict__ wqg_f, signed char* __restrict__ wqo_f,
                            float* __restrict__ dq) {
  if (blockIdx.x < 1472) {
    int i = blockIdx.x * 256 + threadIdx.x;
    if (i < 98304) wih[i] = (__bf16)wih_f[i];                           // [768][128]
    else if (i < 131072) {                                              // Wa[k][a] -> wa_t[a][k]
      int j = i - 98304; int a = j >> 8, k = j & 255;
      wa_t[j] = (__bf16)wa_f[k * 128 + a];
    } else if (i < 147456) {                                            // Ua[f][a] -> ua_t[a][f]
      int j = i - 131072; int a = j >> 7, f = j & 127;
      ua_t[j] = (__bf16)ua_f[f * 128 + a];
    } else if (i < 245760) {                                            // W1[k][c] -> w1_t[c][k]
      int j = i - 147456; int c = j / 384, k = j - c * 384;
      w1_t[j] = (__bf16)w1_f[k * 256 + c];
    } else if (i < 376832) {                                            // W2[k][o] -> w2_t[o][k]
      int j = i - 245760; int o = j >> 8, k = j & 255;
      w2_t[j] = (__bf16)w2_f[k * 512 + o];
    }
    return;
  }
  const int c = (blockIdx.x - 1472) * 256 + threadIdx.x;
  if (c >= 896) return;
  const float* row = (c < 768) ? whh_f + (size_t)c * 256 : wout_f + (size_t)(c - 768) * 256;
  float m = 0.f;
  for (int k4 = 0; k4 < 64; ++k4) {
    float4 v = *(const float4*)(row + k4 * 4);
    m = fmaxf(m, fmaxf(fmaxf(fabsf(v.x), fabsf(v.y)), fmaxf(fabsf(v.z), fabsf(v.w))));
  }
  const float inv = (m > 1e-30f) ? 127.f / m : 0.f;
  dq[c] = m / 16129.f;
  if (c < 768) {
    const int g = c >> 8, cc = c & 255;
    const int t16 = cc >> 4, l15q = cc & 15;
    for (int kt = 0; kt < 4; ++kt)
      for (int lgq = 0; lgq < 4; ++lgq) {
        signed char* dst = wqg_f + (size_t)((((g * 16 + t16) * 4 + kt) * 64) + lgq * 16 + l15q) * 16;
        const float* src = row + kt * 64 + lgq * 16;
        for (int j4 = 0; j4 < 4; ++j4) {
          float4 v = *(const float4*)(src + j4 * 4);
          *(unsigned*)(dst + j4 * 4) = pack4(v.x, v.y, v.z, v.w, inv);
        }
      }
  } else {
    const int oc = c - 768;
    const int t8 = oc >> 4, l15q = oc & 15;
    for (int kt = 0; kt < 4; ++kt)
      for (int lgq = 0; lgq < 4; ++lgq) {
        signed char* dst = wqo_f + (size_t)(((t8 * 4 + kt) * 64) + lgq * 16 + l15q) * 16;
        const float* src = row + kt * 64 + lgq * 16;
        for (int j4 = 0; j4 < 4; ++j4) {
          float4 v = *(const float4*)(src + j4 * 4);
          *(unsigned*)(dst + j4 * 4) = pack4(v.x, v.y, v.z, v.w, inv);
        }
      }
  }
}

// ---- gi precompute (producer layout) + masked zeroing of out ----
__global__ __launch_bounds__(512, 2) void gi_gemm_kernel(
    const float* __restrict__ x, const float* __restrict__ b_ih,
    const float* __restrict__ b_hh, const __bf16* __restrict__ wih,
    const int* __restrict__ tte, __bf16* __restrict__ gi,
    float* __restrict__ out) {
  const int tid = threadIdx.x;
  const int lane = tid & 63, w = tid >> 6;
  const int l15 = lane & 15, lg = lane >> 4, kofs = lg * 8;
  const int bblk = blockIdx.x & 63, tgrp = blockIdx.x >> 6;
  const int b0 = bblk * 16;

  // zero out[b][t][:] for this stripe's (b,t) with t >= tte[b]
  {
    const int pr = tid >> 1, ph = tid & 1;
    const int bl = pr >> 4, tl = pr & 15;
    const int bb = b0 + bl, tt = tgrp * 16 + tl;
    if (tt >= tte[bb]) {
      float4* dst = (float4*)(out + ((size_t)bb * L_ + tt) * F_) + ph * 16;
#pragma unroll
      for (int i = 0; i < 16; ++i) dst[i] = float4{0.f, 0.f, 0.f, 0.f};
    }
  }

  int tmaxB = 0;
  for (int i = 0; i < 16; ++i) tmaxB = max(tmaxB, tte[b0 + i]);
  if (tgrp * 16 > tmaxB) return;

  bf16x8 wf[6][4];
  float bias[6];
#pragma unroll
  for (int tile = 0; tile < 6; ++tile) {
    const int gate = tile >> 1;
    const int c = w * 32 + (tile & 1) * 16 + l15;
    const int col = gate * 256 + c;
#pragma unroll
    for (int kt = 0; kt < 4; ++kt) wf[tile][kt] = ld8(wih + (size_t)col * 128 + kt * 32 + kofs);
    bias[tile] = (gate == 0) ? b_ih[c] + b_hh[c]
               : (gate == 1) ? b_ih[256 + c] + b_hh[256 + c]
                             : b_ih[512 + c];
  }

#pragma unroll 1
  for (int ti = 0; ti < 16; ++ti) {
    const int t = tgrp * 16 + ti;
    if (t > tmaxB) break;
    const float* xb = x + ((size_t)(b0 + l15) * L_ + t) * F_ + kofs;
    bf16x8 xfr[4];
#pragma unroll
    for (int kt = 0; kt < 4; ++kt) {
      float4 a = *(const float4*)(xb + kt * 32);
      float4 b = *(const float4*)(xb + kt * 32 + 4);
      xfr[kt][0] = (__bf16)a.x; xfr[kt][1] = (__bf16)a.y;
      xfr[kt][2] = (__bf16)a.z; xfr[kt][3] = (__bf16)a.w;
      xfr[kt][4] = (__bf16)b.x; xfr[kt][5] = (__bf16)b.y;
      xfr[kt][6] = (__bf16)b.z; xfr[kt][7] = (__bf16)b.w;
    }
    f32x4 acc[6];
#pragma unroll
    for (int tile = 0; tile < 6; ++tile) {
      acc[tile][0] = bias[tile]; acc[tile][1] = bias[tile];
      acc[tile][2] = bias[tile]; acc[tile][3] = bias[tile];
    }
#pragma unroll
    for (int kt = 0; kt < 4; ++kt)
#pragma unroll
      for (int tile = 0; tile < 6; ++tile)
        acc[tile] = MFMA16(xfr[kt], wf[tile][kt], acc[tile]);

    const size_t chunk = (((size_t)t * 64 + bblk) * 8 + w) * 6;
#pragma unroll
    for (int tile = 0; tile < 6; ++tile) {
      bf16x4 pk;
      pk[0] = (__bf16)acc[tile][0]; pk[1] = (__bf16)acc[tile][1];
      pk[2] = (__bf16)acc[tile][2]; pk[3] = (__bf16)acc[tile][3];
      *(bf16x4*)(gi + (chunk + tile) * 256 + (lg * 16 + l15) * 4) = pk;
    }
  }
}

// ---- recurrence gru256v4 (R20-passing): intra-wave shuffle redistribute,
// register-resident i8 weights, ONE barrier/step. ----
__global__ __launch_bounds__(1024) void gru256_kernel(
    const int* __restrict__ tte, const float* __restrict__ b_hh,
    const signed char* __restrict__ wqg_f, const signed char* __restrict__ wqo_f,
    const float* __restrict__ dq, const __bf16* __restrict__ gi,
    const float* __restrict__ b_out,
    __bf16* __restrict__ hid, float* __restrict__ out) {
  __shared__ signed char hb[2][4][288];     // i8 h (2-way-free banking)
  const int tid = threadIdx.x;
  const int lane = tid & 63, w = tid >> 6;          // 16 waves
  const int l15 = lane & 15, lg = lane >> 4;
  const int blk = blockIdx.x;
  const int b0 = blk * 4;

  for (int i = tid; i < 2 * 4 * 288; i += 1024) ((signed char*)hb)[i] = 0;

  i32x4 wR[4], wZ[4], wN[4];
#pragma unroll
  for (int kt = 0; kt < 4; ++kt) {
    wR[kt] = *(const i32x4*)(wqg_f + (size_t)((((0 * 16 + w) * 4 + kt) * 64) + lane) * 16);
    wZ[kt] = *(const i32x4*)(wqg_f + (size_t)((((1 * 16 + w) * 4 + kt) * 64) + lane) * 16);
    wN[kt] = *(const i32x4*)(wqg_f + (size_t)((((2 * 16 + w) * 4 + kt) * 64) + lane) * 16);
  }
  const int ocol = (w & 7) * 16 + l15;
  i32x4 ow[4];
#pragma unroll
  for (int kt = 0; kt < 4; ++kt)
    ow[kt] = *(const i32x4*)(wqo_f + (size_t)(((w & 7) * 4 + kt) * 64 + lane) * 16);
  const float dqo = dq[768 + ocol];
  const float bo = b_out[ocol];
  int tteO[4];
#pragma unroll
  for (int r = 0; r < 4; ++r) tteO[r] = tte[b0 + r];
  float* outp = out + ((size_t)b0 * L_) * F_ + ocol;   // write target t-1; +=F/step

  const int groww = lane >> 4, gcolw = w * 16 + (lane & 15);
  const float dqR = dq[gcolw], dqZ = dq[256 + gcolw], dqN = dq[512 + gcolw];
  const float bhn = b_hh[512 + gcolw];
  const int tteL = tte[b0 + groww];
  int tmax = 0;
#pragma unroll
  for (int i = 0; i < 4; ++i) tmax = max(tmax, tte[b0 + i]);

  const size_t gb0 = (((size_t)(blk >> 2) * 8 + (gcolw >> 5)) * 6 + ((gcolw >> 4) & 1)) * 256
                   + (size_t)((blk & 3) * 16 + (gcolw & 15)) * 4 + groww;
  const __bf16* gp = gi + gb0;
  __bf16 gRn = gp[0], gZn = gp[512], gNn = gp[1024];
  const __bf16* gpp = gp + 786432;      // slab 1

  __bf16* hidp = hid + ((size_t)(b0 + groww) * L_) * H_ + gcolw;
  float hprev = 0.f;

  __syncthreads();

#pragma unroll 1
  for (int t = 0; t < tmax; ++t) {
    const int c = t & 1, nc = c ^ 1;

    const float grf = (float)gRn, gzf = (float)gZn, gnf = (float)gNn;
    gRn = gpp[0]; gZn = gpp[512]; gNn = gpp[1024];
    if (t < 254) gpp += 786432;   // clamp at slab 255

    i32x4 aR = {0, 0, 0, 0}, aZ = {0, 0, 0, 0}, aN = {0, 0, 0, 0}, ac = {0, 0, 0, 0};
#pragma unroll
    for (int kt = 0; kt < 4; ++kt) {
      const i32x4 hA = *(const i32x4*)&hb[c][l15 & 3][kt * 64 + lg * 16];
      aR = MFMA_I8(hA, wR[kt], aR);
      aZ = MFMA_I8(hA, wZ[kt], aZ);
      aN = MFMA_I8(hA, wN[kt], aN);
      if (w < 8) ac = MFMA_I8(hA, ow[kt], ac);
    }
    if (w < 8 && t > 0) {
      if (lg == 0) {
#pragma unroll
        for (int r = 0; r < 4; ++r)
          if (t - 1 < tteO[r]) outp[(size_t)r * (L_ * F_)] = (float)ac[r] * dqo + bo;
      }
      outp += F_;
    }

    {
      const int srcl = lane & 15;
      int tR0 = __shfl(aR[0], srcl), tR1 = __shfl(aR[1], srcl);
      int tR2 = __shfl(aR[2], srcl), tR3 = __shfl(aR[3], srcl);
      int tZ0 = __shfl(aZ[0], srcl), tZ1 = __shfl(aZ[1], srcl);
      int tZ2 = __shfl(aZ[2], srcl), tZ3 = __shfl(aZ[3], srcl);
      int tN0 = __shfl(aN[0], srcl), tN1 = __shfl(aN[1], srcl);
      int tN2 = __shfl(aN[2], srcl), tN3 = __shfl(aN[3], srcl);
      const int vR = groww == 0 ? tR0 : groww == 1 ? tR1 : groww == 2 ? tR2 : tR3;
      const int vZ = groww == 0 ? tZ0 : groww == 1 ? tZ1 : groww == 2 ? tZ2 : tZ3;
      const int vN = groww == 0 ? tN0 : groww == 1 ? tN1 : groww == 2 ? tN2 : tN3;

      const float rg = sigm(grf + (float)vR * dqR);
      const float zg = sigm(gzf + (float)vZ * dqZ);
      const float ng = tanh_f(gnf + rg * ((float)vN * dqN + bhn));
      const float hnew = zg * (hprev - ng) + ng;
      const float hw = (t < tteL) ? hnew : hprev;
      hprev = hw;
      hb[nc][groww][gcolw] = (signed char)__float2int_rn(hw * 127.f);
      if (t < tteL) *hidp = (__bf16)hw;
      hidp += H_;
    }
    BAR_LDS();   // hb[nc] ready for next step (single barrier/step)
  }

  // epilogue: out-proj for the final step (reads hb[tmax&1] = h(tmax))
  if (w < 8 && tmax > 0) {
    const int cf = tmax & 1;
    i32x4 ac = {0, 0, 0, 0};
#pragma unroll
    for (int kt = 0; kt < 4; ++kt) {
      const i32x4 hA = *(const i32x4*)&hb[cf][l15 & 3][kt * 64 + lg * 16];
      ac = MFMA_I8(hA, ow[kt], ac);
    }
    if (lg == 0) {
#pragma unroll
      for (int r = 0; r < 4; ++r)
        if (tmax - 1 < tteO[r]) outp[(size_t)r * (L_ * F_)] = (float)ac[r] * dqo + bo;
    }
  }
}

// ---- decoder3: 4 batch rows per block, 256 blocks (1/CU). MFMA-batched
// GEMVs; phase E 2-way split per b. All hid reads tte-masked. ----
__global__ __launch_bounds__(512, 2) void decoder3_kernel(
    const float* __restrict__ x, const int* __restrict__ tte,
    const __bf16* __restrict__ hid, const __bf16* __restrict__ wa_t,
    const __bf16* __restrict__ ua_t, const __bf16* __restrict__ w1_t,
    const __bf16* __restrict__ w2_t, const float* __restrict__ va,
    const float* __restrict__ b1, const float* __restrict__ b2,
    float* __restrict__ fht) {
  __shared__ __bf16 catb[16][392];   // rows 0-3: [0..256) ctx | [256..384) last
  __shared__ float u_s[4][128];
  __shared__ float sa[4][256];
  __shared__ __bf16 z1b[16][264];
  __shared__ float lg2[4][516];
  __shared__ float ctxp[2][4][256];
  __shared__ float va_s[128];
  __shared__ int tte_s[4];
  const int tid = threadIdx.x;
  const int lane = tid & 63, w = tid >> 6;
  const int l15 = lane & 15, lg = lane >> 4, kofs = lg * 8;
  const int b0 = blockIdx.x * 4;

  if (tid < 4) tte_s[tid] = tte[b0 + tid];
  if (tid < 128) va_s[tid] = va[tid];
  if (tid < 392)
    for (int r = 4; r < 16; ++r) catb[r][tid] = (__bf16)0.f;
  if (tid < 264)
    for (int r = 4; r < 16; ++r) z1b[r][tid] = (__bf16)0.f;
  __syncthreads();

  // Phase A: gather last -> catb[b][256+f]
  {
    const int row = tid >> 7, c = tid & 127;
    catb[row][256 + c] = (__bf16)x[((size_t)(b0 + row) * L_ + tte_s[row]) * F_ + c];
  }
  __syncthreads();

  // Phase B: u[4][128] = last @ Ua
  {
    f32x4 uacc = {0, 0, 0, 0};
#pragma unroll
    for (int kt = 0; kt < 4; ++kt) {
      const bf16x8 af = *(const bf16x8*)&catb[l15][256 + kt * 32 + kofs];
      const bf16x8 bf = ld8(ua_t + (size_t)(w * 16 + l15) * 128 + kt * 32 + kofs);
      uacc = MFMA16(af, bf, uacc);
    }
#pragma unroll
    for (int r = 0; r < 4; ++r) {
      const int row = 4 * lg + r;
      if (row < 4) u_s[row][w * 16 + l15] = uacc[r];
    }
  }
  __syncthreads();

  // Phase C: attention scores (4 b x 16 mtiles = 64 pairs / 8 waves)
  bf16x8 zero8;
#pragma unroll
  for (int j = 0; j < 8; ++j) zero8[j] = (__bf16)0.f;
#pragma unroll 1
  for (int it = 0; it < 8; ++it) {
    const int pair = it * 8 + w;
    const int b = pair >> 4, mtile = pair & 15;
    const int tteB = tte_s[b];
    const int trow = mtile * 16 + l15;
    const __bf16* hrow = hid + ((size_t)(b0 + b) * L_ + trow) * H_ + kofs;
    bf16x8 af[8];
#pragma unroll
    for (int kt = 0; kt < 8; ++kt) af[kt] = (trow < tteB) ? ld8(hrow + kt * 32) : zero8;
    f32x4 sacc[8];
#pragma unroll
    for (int ct = 0; ct < 8; ++ct) { sacc[ct][0] = 0; sacc[ct][1] = 0; sacc[ct][2] = 0; sacc[ct][3] = 0; }
#pragma unroll
    for (int kt = 0; kt < 8; ++kt)
#pragma unroll
      for (int ct = 0; ct < 8; ++ct)
        sacc[ct] = MFMA16(af[kt], ld8(wa_t + (size_t)(ct * 16 + l15) * 256 + kt * 32 + kofs), sacc[ct]);
    float sp[4] = {0, 0, 0, 0};
#pragma unroll
    for (int ct = 0; ct < 8; ++ct) {
      const int a = ct * 16 + l15;
      const float ua = u_s[b][a], vv = va_s[a];
#pragma unroll
      for (int r = 0; r < 4; ++r) sp[r] += tanh_f(sacc[ct][r] + ua) * vv;
    }
#pragma unroll
    for (int r = 0; r < 4; ++r) {
      sp[r] += __shfl_xor(sp[r], 1);
      sp[r] += __shfl_xor(sp[r], 2);
      sp[r] += __shfl_xor(sp[r], 4);
      sp[r] += __shfl_xor(sp[r], 8);
    }
    if (l15 == 0) {
#pragma unroll
      for (int r = 0; r < 4; ++r) sa[b][mtile * 16 + 4 * lg + r] = sp[r];
    }
  }
  __syncthreads();

  // Phase D: softmax per b (waves 0-3)
  if (w < 4) {
    float sv[4];
#pragma unroll
    for (int j = 0; j < 4; ++j) sv[j] = sa[w][lane + 64 * j];
    float mx = fmaxf(fmaxf(sv[0], sv[1]), fmaxf(sv[2], sv[3]));
    mx = wave_max(mx);
    float es[4], ss = 0.f;
#pragma unroll
    for (int j = 0; j < 4; ++j) { es[j] = __expf(sv[j] - mx); ss += es[j]; }
    ss = wave_sum(ss);
    const float inv = rcp_f(ss);
#pragma unroll
    for (int j = 0; j < 4; ++j) sa[w][lane + 64 * j] = es[j] * inv;
  }
  __syncthreads();

  // Phase E: ctx partials — wave w: b = w&3, half = w>>2
  {
    const int be = w & 3, half = w >> 2;
    const int tteE = tte_s[be];
    float c4[4] = {0.f, 0.f, 0.f, 0.f};
    const __bf16* hp = hid + ((size_t)(b0 + be) * L_ + half) * H_ + lane * 4;
#pragma unroll 2
    for (int t = half; t < tteE; t += 2) {
      const float al = sa[be][t];
      const bf16x4 hv = *(const bf16x4*)hp;
      hp += 2 * H_;
#pragma unroll
      for (int j = 0; j < 4; ++j) c4[j] += al * (float)hv[j];
    }
#pragma unroll
    for (int j = 0; j < 4; ++j) ctxp[half][be][lane * 4 + j] = c4[j];
  }
  __syncthreads();
  if (w < 4) {
#pragma unroll
    for (int j = 0; j < 4; ++j)
      catb[w][lane * 4 + j] = (__bf16)(ctxp[0][w][lane * 4 + j] + ctxp[1][w][lane * 4 + j]);
  }
  __syncthreads();

  // Phase F: z1 = relu([ctx|last] @ W1 + b1)
#pragma unroll 1
  for (int half = 0; half < 2; ++half) {
    const int nt = w * 2 + half;
    f32x4 zacc = {0, 0, 0, 0};
#pragma unroll
    for (int kt = 0; kt < 12; ++kt) {
      const bf16x8 af = *(const bf16x8*)&catb[l15][kt * 32 + kofs];
      const bf16x8 bf = ld8(w1_t + (size_t)(nt * 16 + l15) * 384 + kt * 32 + kofs);
      zacc = MFMA16(af, bf, zacc);
    }
    const float bb = b1[nt * 16 + l15];
#pragma unroll
    for (int r = 0; r < 4; ++r) {
      const int row = 4 * lg + r;
      if (row < 4) z1b[row][nt * 16 + l15] = (__bf16)fmaxf(zacc[r] + bb, 0.f);
    }
  }
  __syncthreads();

  // Phase G: logits + final softmax
#pragma unroll 1
  for (int q = 0; q < 4; ++q) {
    const int nt = w * 4 + q;
    f32x4 oacc = {0, 0, 0, 0};
#pragma unroll
    for (int kt = 0; kt < 8; ++kt) {
      const bf16x8 af = *(const bf16x8*)&z1b[l15][kt * 32 + kofs];
      const bf16x8 bf = ld8(w2_t + (size_t)(nt * 16 + l15) * 256 + kt * 32 + kofs);
      oacc = MFMA16(af, bf, oacc);
    }
    const float bb = b2[nt * 16 + l15];
#pragma unroll
    for (int r = 0; r < 4; ++r) {
      const int row = 4 * lg + r;
      if (row < 4) lg2[row][nt * 16 + l15] = oacc[r] + bb;
    }
  }
  __syncthreads();
  if (w < 4) {
    float lv[8];
    float mx = -1e30f;
#pragma unroll
    for (int j = 0; j < 8; ++j) { lv[j] = lg2[w][lane + 64 * j]; mx = fmaxf(mx, lv[j]); }
    mx = wave_max(mx);
    float s2 = 0.f;
#pragma unroll
    for (int j = 0; j < 8; ++j) { lv[j] = __expf(lv[j] - mx); s2 += lv[j]; }
    s2 = wave_sum(s2);
    const float inv2 = rcp_f(s2);
#pragma unroll
    for (int j = 0; j < 8; ++j)
      fht[(size_t)(b0 + w) * 512 + lane + 64 * j] = lv[j] * inv2;
  }
}

extern "C" void kernel_launch(void* const* d_in, const int* in_sizes, int n_in,
                              void* d_out, int out_size, void* d_ws, size_t ws_size,
                              hipStream_t stream) {
  const float* x = (const float*)d_in[0];
  const int* tte = (const int*)d_in[1];
  const float* W_ih = (const float*)d_in[2];
  const float* W_hh = (const float*)d_in[3];
  const float* b_ih = (const float*)d_in[4];
  const float* b_hh = (const float*)d_in[5];
  const float* W_out = (const float*)d_in[6];
  const float* b_out = (const float*)d_in[7];
  const float* Wa = (const float*)d_in[8];
  const float* Ua = (const float*)d_in[9];
  const float* va = (const float*)d_in[10];
  const float* W1 = (const float*)d_in[11];
  const float* b1 = (const float*)d_in[12];
  const float* W2 = (const float*)d_in[13];
  const float* b2 = (const float*)d_in[14];

  char* ws = (char*)d_ws;
  __bf16* wih = (__bf16*)(ws + 0);                  // 196608
  __bf16* wa_t = (__bf16*)(ws + 196608);            // 65536
  __bf16* ua_t = (__bf16*)(ws + 262144);            // 32768
  __bf16* w1_t = (__bf16*)(ws + 294912);            // 196608
  __bf16* w2_t = (__bf16*)(ws + 491520);            // 262144
  signed char* wqg_f = (signed char*)(ws + 753664); // 196608
  signed char* wqo_f = (signed char*)(ws + 950272); // 32768
  float* dq = (float*)(ws + 983040);                // 3584 used
  __bf16* hid = (__bf16*)(ws + 1048576);            // 134217728
  __bf16* gi = (__bf16*)(ws + 135266304);           // 402653184

  float* out = (float*)d_out;
  float* fht = out + (size_t)33554432;

  prep_kernel<<<1476, 256, 0, stream>>>(W_ih, Wa, Ua, W1, W2, W_hh, W_out,
                                        wih, wa_t, ua_t, w1_t, w2_t,
                                        wqg_f, wqo_f, dq);
  gi_gemm_kernel<<<1024, 512, 0, stream>>>(x, b_ih, b_hh, wih, tte, gi, out);
  gru256_kernel<<<256, 1024, 0, stream>>>(tte, b_hh, wqg_f, wqo_f, dq, gi,
                                          b_out, hid, out);
  decoder3_kernel<<<256, 512, 0, stream>>>(x, tte, hid, wa_t, ua_t, w1_t, w2_t,
                                           va, b1, b2, fht);
}